// Round 1
// baseline (255.596 us; speedup 1.0000x reference)
//
#include <hip/hip_runtime.h>
#include <math.h>

// Output = segment_softmax over logits that depend ONLY on the inputs part of
// combined @ W_k: the agg(segment-mean MLP) contribution is constant within a
// segment and cancels exactly in the segment softmax (shift invariance).
// wx[d][h] = sum_j Wk[d, h*64+j]*Wq[h,j] / 8;  logit[n,h] = x[n,:].wx[:,h];
// per-segment softmax; out[h*N + n].
//
// Round 4: block-per-segment (2048 blocks, 4 waves each, one row per thread).
//  - cache loop is compile-time unrolled (CACHE_IT=2 -> 512 rows) so the
//    logit cache stays in VGPRs (runtime-indexed cache was spilling to
//    scratch in the wave-per-segment version).
//  - occupancy 8 blocks/CU = 32 waves/CU (vs 2 blocks/CU before).
//  - reductions: wave shfl_xor + 4-entry LDS combine, 3 barriers/block total.

#define NROWS 500000
#define DIM 40
#define NSEG 2048
#define DOTD 64
#define NH 4
#define BLOCK 256
#define NWAVE (BLOCK / 64)
#define CACHE_IT 2      // 2*256 = 512 rows fast path (stat max ~300)

// ---- prep: segment bounds (with gap fill for empty segments) + wx fold ----
__global__ __launch_bounds__(BLOCK) void prep_kernel(
    const int* __restrict__ seg,    // [N], sorted
    const float* __restrict__ Wk,   // [168, 256]
    const float* __restrict__ Wq,   // [4, 64]
    int* __restrict__ seg_start,    // [NSEG]
    int* __restrict__ seg_end,      // [NSEG]
    float* __restrict__ wxg)        // [DIM*NH], layout d*4+h
{
    const int tid = (int)threadIdx.x;
    const int n = (int)(blockIdx.x * BLOCK + tid);

    if (blockIdx.x == 0 && tid < DIM * NH) {
        const int d = tid >> 2;
        const int h = tid & 3;
        const float* wkp = Wk + d * (NH * DOTD) + h * DOTD;
        const float* wqp = Wq + h * DOTD;
        float acc = 0.f;
        #pragma unroll
        for (int j = 0; j < DOTD; ++j) acc += wkp[j] * wqp[j];
        wxg[tid] = acc * 0.125f;  // fold 1/sqrt(64)
    }

    if (n < NROWS) {
        const int s = seg[n];
        if (n == 0) {
            seg_start[s] = 0;
            for (int t = 0; t < s; ++t) { seg_start[t] = 0; seg_end[t] = 0; }
        } else {
            const int sp = seg[n - 1];
            if (sp != s) {
                seg_start[s] = n;
                seg_end[sp] = n;
                for (int t = sp + 1; t < s; ++t) { seg_start[t] = n; seg_end[t] = n; }
            }
        }
        if (n == NROWS - 1) {
            seg_end[s] = NROWS;
            for (int t = s + 1; t < NSEG; ++t) { seg_start[t] = NROWS; seg_end[t] = NROWS; }
        }
    }
}

__device__ __forceinline__ void compute_logits(
    const float* __restrict__ x, int n, const float (*wx)[NH], float* acc)
{
    const float4* xr = (const float4*)(x + (size_t)n * DIM);
    #pragma unroll
    for (int h = 0; h < NH; ++h) acc[h] = 0.f;
    #pragma unroll
    for (int q = 0; q < DIM / 4; ++q) {
        const float4 v = xr[q];
        #pragma unroll
        for (int h = 0; h < NH; ++h) {
            acc[h] += v.x * wx[4 * q + 0][h];
            acc[h] += v.y * wx[4 * q + 1][h];
            acc[h] += v.z * wx[4 * q + 2][h];
            acc[h] += v.w * wx[4 * q + 3][h];
        }
    }
}

// ---- main: one block (4 waves) per segment, one row per thread ----
__global__ __launch_bounds__(BLOCK, 8) void seg_attn_kernel(
    const float* __restrict__ x,          // [N, 40]
    const int* __restrict__ seg_start,
    const int* __restrict__ seg_end,
    const float* __restrict__ wxg,        // [DIM*NH]
    float* __restrict__ out)              // [4, N]
{
    __shared__ float wx[DIM][NH];
    __shared__ float red_max[NWAVE][NH];
    __shared__ float red_sum[NWAVE][NH];

    const int tid = (int)threadIdx.x;
    if (tid < DIM * NH) wx[tid >> 2][tid & 3] = wxg[tid];

    const int s = (int)blockIdx.x;
    const int start = seg_start[s];
    const int rows = seg_end[s] - start;
    __syncthreads();
    if (rows <= 0) return;   // block-uniform exit (all threads see same rows)

    const int lane = tid & 63;
    const int wid = tid >> 6;
    const int iters = (rows + BLOCK - 1) / BLOCK;   // 1 for rows<=256 (common)

    // ---- pass 1: logits + lane-local max (cache fully register-resident) ----
    float cache[CACHE_IT][NH];
    float lmax[NH];
    #pragma unroll
    for (int h = 0; h < NH; ++h) lmax[h] = -3.0e38f;

    #pragma unroll
    for (int it = 0; it < CACHE_IT; ++it) {         // compile-time trip count
        const int i = it * BLOCK + tid;
        if (i < rows) {
            float acc[NH];
            compute_logits(x, start + i, wx, acc);
            #pragma unroll
            for (int h = 0; h < NH; ++h) {
                cache[it][h] = acc[h];              // static index -> VGPR
                lmax[h] = fmaxf(lmax[h], acc[h]);
            }
        }
    }
    for (int it = CACHE_IT; it < iters; ++it) {     // stat-never fallback
        const int i = it * BLOCK + tid;
        if (i < rows) {
            float acc[NH];
            compute_logits(x, start + i, wx, acc);
            #pragma unroll
            for (int h = 0; h < NH; ++h) lmax[h] = fmaxf(lmax[h], acc[h]);
        }
    }

    // ---- block max reduce: wave shfl + LDS combine ----
    #pragma unroll
    for (int h = 0; h < NH; ++h) {
        float v = lmax[h];
        #pragma unroll
        for (int off = 32; off > 0; off >>= 1) v = fmaxf(v, __shfl_xor(v, off, 64));
        if (lane == 0) red_max[wid][h] = v;
    }
    __syncthreads();
    float m[NH];
    #pragma unroll
    for (int h = 0; h < NH; ++h)
        m[h] = fmaxf(fmaxf(red_max[0][h], red_max[1][h]),
                     fmaxf(red_max[2][h], red_max[3][h]));

    // ---- pass 2: exp + block sum; cache holds exp(l-m) afterwards ----
    float lsum[NH] = {0.f, 0.f, 0.f, 0.f};
    #pragma unroll
    for (int it = 0; it < CACHE_IT; ++it) {
        const int i = it * BLOCK + tid;
        if (i < rows) {
            #pragma unroll
            for (int h = 0; h < NH; ++h) {
                const float e = __expf(cache[it][h] - m[h]);
                cache[it][h] = e;
                lsum[h] += e;
            }
        }
    }
    for (int it = CACHE_IT; it < iters; ++it) {
        const int i = it * BLOCK + tid;
        if (i < rows) {
            float acc[NH];
            compute_logits(x, start + i, wx, acc);
            #pragma unroll
            for (int h = 0; h < NH; ++h) lsum[h] += __expf(acc[h] - m[h]);
        }
    }

    #pragma unroll
    for (int h = 0; h < NH; ++h) {
        float v = lsum[h];
        #pragma unroll
        for (int off = 32; off > 0; off >>= 1) v += __shfl_xor(v, off, 64);
        if (lane == 0) red_sum[wid][h] = v;
    }
    __syncthreads();
    float rden[NH];
    #pragma unroll
    for (int h = 0; h < NH; ++h)
        rden[h] = 1.0f / (red_sum[0][h] + red_sum[1][h] +
                          red_sum[2][h] + red_sum[3][h]);

    // ---- pass 3: write normalized outputs (coalesced per h) ----
    #pragma unroll
    for (int it = 0; it < CACHE_IT; ++it) {
        const int i = it * BLOCK + tid;
        if (i < rows) {
            const int n = start + i;
            #pragma unroll
            for (int h = 0; h < NH; ++h)
                out[(size_t)h * NROWS + n] = cache[it][h] * rden[h];
        }
    }
    for (int it = CACHE_IT; it < iters; ++it) {
        const int i = it * BLOCK + tid;
        if (i < rows) {
            float acc[NH];
            compute_logits(x, start + i, wx, acc);
            const int n = start + i;
            #pragma unroll
            for (int h = 0; h < NH; ++h)
                out[(size_t)h * NROWS + n] = __expf(acc[h] - m[h]) * rden[h];
        }
    }
}

extern "C" void kernel_launch(void* const* d_in, const int* in_sizes, int n_in,
                              void* d_out, int out_size, void* d_ws, size_t ws_size,
                              hipStream_t stream) {
    const float* x  = (const float*)d_in[0];
    const int* seg  = (const int*)d_in[1];
    const float* Wk = (const float*)d_in[11];
    const float* Wq = (const float*)d_in[12];
    float* out = (float*)d_out;

    int* seg_start = (int*)d_ws;                  // [NSEG]
    int* seg_end   = seg_start + NSEG;            // [NSEG]
    float* wxg     = (float*)(seg_end + NSEG);    // [DIM*NH]

    hipLaunchKernelGGL(prep_kernel, dim3((NROWS + BLOCK - 1) / BLOCK), dim3(BLOCK),
                       0, stream, seg, Wk, Wq, seg_start, seg_end, wxg);
    hipLaunchKernelGGL(seg_attn_kernel, dim3(NSEG), dim3(BLOCK),
                       0, stream, x, seg_start, seg_end, wxg, out);
}

// Round 2
// 197.132 us; speedup vs baseline: 1.2966x; 1.2966x over previous
//
#include <hip/hip_runtime.h>
#include <math.h>

// Output = segment_softmax over logits that depend ONLY on the inputs part of
// combined @ W_k: the agg(segment-mean MLP) contribution is constant within a
// segment and cancels exactly in the segment softmax (shift invariance).
// wx[d][h] = sum_j Wk[d, h*64+j]*Wq[h,j] / 8;  logit[n,h] = x[n,:].wx[:,h];
// per-segment softmax; out[h*N + n].
//
// Round 5: block-per-segment, SPILL FIX.
//  Round 4's __launch_bounds__(256,8) capped VGPRs at 64 -> allocator picked
//  32 and spilled the register cache to scratch (WRITE_SIZE 213MB vs 8MB
//  ideal, FETCH 250MB vs 88MB; latency-bound at 3.3TB/s). Relax to
//  min-waves=4 (VGPR budget 128) so cache[2][4]+acc+reductions stay in VGPRs.

#define NROWS 500000
#define DIM 40
#define NSEG 2048
#define DOTD 64
#define NH 4
#define BLOCK 256
#define NWAVE (BLOCK / 64)
#define CACHE_IT 2      // 2*256 = 512 rows fast path (stat max ~300)

// ---- prep: segment bounds (with gap fill for empty segments) + wx fold ----
__global__ __launch_bounds__(BLOCK) void prep_kernel(
    const int* __restrict__ seg,    // [N], sorted
    const float* __restrict__ Wk,   // [168, 256]
    const float* __restrict__ Wq,   // [4, 64]
    int* __restrict__ seg_start,    // [NSEG]
    int* __restrict__ seg_end,      // [NSEG]
    float* __restrict__ wxg)        // [DIM*NH], layout d*4+h
{
    const int tid = (int)threadIdx.x;
    const int n = (int)(blockIdx.x * BLOCK + tid);

    if (blockIdx.x == 0 && tid < DIM * NH) {
        const int d = tid >> 2;
        const int h = tid & 3;
        const float* wkp = Wk + d * (NH * DOTD) + h * DOTD;
        const float* wqp = Wq + h * DOTD;
        float acc = 0.f;
        #pragma unroll
        for (int j = 0; j < DOTD; ++j) acc += wkp[j] * wqp[j];
        wxg[tid] = acc * 0.125f;  // fold 1/sqrt(64)
    }

    if (n < NROWS) {
        const int s = seg[n];
        if (n == 0) {
            seg_start[s] = 0;
            for (int t = 0; t < s; ++t) { seg_start[t] = 0; seg_end[t] = 0; }
        } else {
            const int sp = seg[n - 1];
            if (sp != s) {
                seg_start[s] = n;
                seg_end[sp] = n;
                for (int t = sp + 1; t < s; ++t) { seg_start[t] = n; seg_end[t] = n; }
            }
        }
        if (n == NROWS - 1) {
            seg_end[s] = NROWS;
            for (int t = s + 1; t < NSEG; ++t) { seg_start[t] = NROWS; seg_end[t] = NROWS; }
        }
    }
}

__device__ __forceinline__ void compute_logits(
    const float* __restrict__ x, int n, const float (*wx)[NH], float* acc)
{
    const float4* xr = (const float4*)(x + (size_t)n * DIM);
    #pragma unroll
    for (int h = 0; h < NH; ++h) acc[h] = 0.f;
    #pragma unroll
    for (int q = 0; q < DIM / 4; ++q) {
        const float4 v = xr[q];
        #pragma unroll
        for (int h = 0; h < NH; ++h) {
            acc[h] += v.x * wx[4 * q + 0][h];
            acc[h] += v.y * wx[4 * q + 1][h];
            acc[h] += v.z * wx[4 * q + 2][h];
            acc[h] += v.w * wx[4 * q + 3][h];
        }
    }
}

// ---- main: one block (4 waves) per segment, one row per thread ----
__global__ __launch_bounds__(BLOCK, 4) void seg_attn_kernel(
    const float* __restrict__ x,          // [N, 40]
    const int* __restrict__ seg_start,
    const int* __restrict__ seg_end,
    const float* __restrict__ wxg,        // [DIM*NH]
    float* __restrict__ out)              // [4, N]
{
    __shared__ float wx[DIM][NH];
    __shared__ float red_max[NWAVE][NH];
    __shared__ float red_sum[NWAVE][NH];

    const int tid = (int)threadIdx.x;
    if (tid < DIM * NH) wx[tid >> 2][tid & 3] = wxg[tid];

    const int s = (int)blockIdx.x;
    const int start = seg_start[s];
    const int rows = seg_end[s] - start;
    __syncthreads();
    if (rows <= 0) return;   // block-uniform exit (all threads see same rows)

    const int lane = tid & 63;
    const int wid = tid >> 6;
    const int iters = (rows + BLOCK - 1) / BLOCK;   // 1 for rows<=256 (common)

    // ---- pass 1: logits + lane-local max (cache fully register-resident) ----
    float cache[CACHE_IT][NH];
    float lmax[NH];
    #pragma unroll
    for (int h = 0; h < NH; ++h) lmax[h] = -3.0e38f;

    #pragma unroll
    for (int it = 0; it < CACHE_IT; ++it) {         // compile-time trip count
        const int i = it * BLOCK + tid;
        if (i < rows) {
            float acc[NH];
            compute_logits(x, start + i, wx, acc);
            #pragma unroll
            for (int h = 0; h < NH; ++h) {
                cache[it][h] = acc[h];              // static index -> VGPR
                lmax[h] = fmaxf(lmax[h], acc[h]);
            }
        }
    }
    for (int it = CACHE_IT; it < iters; ++it) {     // stat-never fallback
        const int i = it * BLOCK + tid;
        if (i < rows) {
            float acc[NH];
            compute_logits(x, start + i, wx, acc);
            #pragma unroll
            for (int h = 0; h < NH; ++h) lmax[h] = fmaxf(lmax[h], acc[h]);
        }
    }

    // ---- block max reduce: wave shfl + LDS combine ----
    #pragma unroll
    for (int h = 0; h < NH; ++h) {
        float v = lmax[h];
        #pragma unroll
        for (int off = 32; off > 0; off >>= 1) v = fmaxf(v, __shfl_xor(v, off, 64));
        if (lane == 0) red_max[wid][h] = v;
    }
    __syncthreads();
    float m[NH];
    #pragma unroll
    for (int h = 0; h < NH; ++h)
        m[h] = fmaxf(fmaxf(red_max[0][h], red_max[1][h]),
                     fmaxf(red_max[2][h], red_max[3][h]));

    // ---- pass 2: exp + block sum; cache holds exp(l-m) afterwards ----
    float lsum[NH] = {0.f, 0.f, 0.f, 0.f};
    #pragma unroll
    for (int it = 0; it < CACHE_IT; ++it) {
        const int i = it * BLOCK + tid;
        if (i < rows) {
            #pragma unroll
            for (int h = 0; h < NH; ++h) {
                const float e = __expf(cache[it][h] - m[h]);
                cache[it][h] = e;
                lsum[h] += e;
            }
        }
    }
    for (int it = CACHE_IT; it < iters; ++it) {
        const int i = it * BLOCK + tid;
        if (i < rows) {
            float acc[NH];
            compute_logits(x, start + i, wx, acc);
            #pragma unroll
            for (int h = 0; h < NH; ++h) lsum[h] += __expf(acc[h] - m[h]);
        }
    }

    #pragma unroll
    for (int h = 0; h < NH; ++h) {
        float v = lsum[h];
        #pragma unroll
        for (int off = 32; off > 0; off >>= 1) v += __shfl_xor(v, off, 64);
        if (lane == 0) red_sum[wid][h] = v;
    }
    __syncthreads();
    float rden[NH];
    #pragma unroll
    for (int h = 0; h < NH; ++h)
        rden[h] = 1.0f / (red_sum[0][h] + red_sum[1][h] +
                          red_sum[2][h] + red_sum[3][h]);

    // ---- pass 3: write normalized outputs (coalesced per h) ----
    #pragma unroll
    for (int it = 0; it < CACHE_IT; ++it) {
        const int i = it * BLOCK + tid;
        if (i < rows) {
            const int n = start + i;
            #pragma unroll
            for (int h = 0; h < NH; ++h)
                out[(size_t)h * NROWS + n] = cache[it][h] * rden[h];
        }
    }
    for (int it = CACHE_IT; it < iters; ++it) {
        const int i = it * BLOCK + tid;
        if (i < rows) {
            float acc[NH];
            compute_logits(x, start + i, wx, acc);
            const int n = start + i;
            #pragma unroll
            for (int h = 0; h < NH; ++h)
                out[(size_t)h * NROWS + n] = __expf(acc[h] - m[h]) * rden[h];
        }
    }
}

extern "C" void kernel_launch(void* const* d_in, const int* in_sizes, int n_in,
                              void* d_out, int out_size, void* d_ws, size_t ws_size,
                              hipStream_t stream) {
    const float* x  = (const float*)d_in[0];
    const int* seg  = (const int*)d_in[1];
    const float* Wk = (const float*)d_in[11];
    const float* Wq = (const float*)d_in[12];
    float* out = (float*)d_out;

    int* seg_start = (int*)d_ws;                  // [NSEG]
    int* seg_end   = seg_start + NSEG;            // [NSEG]
    float* wxg     = (float*)(seg_end + NSEG);    // [DIM*NH]

    hipLaunchKernelGGL(prep_kernel, dim3((NROWS + BLOCK - 1) / BLOCK), dim3(BLOCK),
                       0, stream, seg, Wk, Wq, seg_start, seg_end, wxg);
    hipLaunchKernelGGL(seg_attn_kernel, dim3(NSEG), dim3(BLOCK),
                       0, stream, x, seg_start, seg_end, wxg, out);
}

// Round 3
// 170.703 us; speedup vs baseline: 1.4973x; 1.1548x over previous
//
#include <hip/hip_runtime.h>
#include <math.h>

// Output = segment_softmax over logits that depend ONLY on the inputs part of
// combined @ W_k: the agg(segment-mean MLP) contribution is constant within a
// segment and cancels exactly in the segment softmax (shift invariance).
// wx[d][h] = sum_j Wk[d, h*64+j]*Wq[h,j] / 8;  logit[n,h] = x[n,:].wx[:,h];
// per-segment softmax; out[h*N + n].
//
// Round 6: block-per-segment with LDS logit cache.
//  Rounds 4/5 tried to keep the per-row logit cache in VGPRs; the allocator
//  spilled it to scratch both times (WRITE_SIZE 213MB @ VGPR=32, 110MB @
//  VGPR=64 vs 8MB ideal -> latency-bound at 2.2TB/s, VALUBusy 5%).
//  A row-indexed per-block cache belongs in LDS: cache_l[NH][512] = 8KB,
//  conflict-free (consecutive lanes -> consecutive 4B per head plane).
//  Register state drops to ~30 VGPRs; no launch_bounds clamp needed.
//  Pass 3 recomputes exp from the cached logit (cheap) to skip an LDS write.

#define NROWS 500000
#define DIM 40
#define NSEG 2048
#define DOTD 64
#define NH 4
#define BLOCK 256
#define NWAVE (BLOCK / 64)
#define CACHE_ROWS 512   // stat max segment len ~300 (binomial mean 244, sd 16)

// ---- prep: segment bounds (with gap fill for empty segments) + wx fold ----
__global__ __launch_bounds__(BLOCK) void prep_kernel(
    const int* __restrict__ seg,    // [N], sorted
    const float* __restrict__ Wk,   // [168, 256]
    const float* __restrict__ Wq,   // [4, 64]
    int* __restrict__ seg_start,    // [NSEG]
    int* __restrict__ seg_end,      // [NSEG]
    float* __restrict__ wxg)        // [DIM*NH], layout d*4+h
{
    const int tid = (int)threadIdx.x;
    const int n = (int)(blockIdx.x * BLOCK + tid);

    if (blockIdx.x == 0 && tid < DIM * NH) {
        const int d = tid >> 2;
        const int h = tid & 3;
        const float* wkp = Wk + d * (NH * DOTD) + h * DOTD;
        const float* wqp = Wq + h * DOTD;
        float acc = 0.f;
        #pragma unroll
        for (int j = 0; j < DOTD; ++j) acc += wkp[j] * wqp[j];
        wxg[tid] = acc * 0.125f;  // fold 1/sqrt(64)
    }

    if (n < NROWS) {
        const int s = seg[n];
        if (n == 0) {
            seg_start[s] = 0;
            for (int t = 0; t < s; ++t) { seg_start[t] = 0; seg_end[t] = 0; }
        } else {
            const int sp = seg[n - 1];
            if (sp != s) {
                seg_start[s] = n;
                seg_end[sp] = n;
                for (int t = sp + 1; t < s; ++t) { seg_start[t] = n; seg_end[t] = n; }
            }
        }
        if (n == NROWS - 1) {
            seg_end[s] = NROWS;
            for (int t = s + 1; t < NSEG; ++t) { seg_start[t] = NROWS; seg_end[t] = NROWS; }
        }
    }
}

__device__ __forceinline__ void compute_logits(
    const float* __restrict__ x, int n, const float (*wx)[NH], float* acc)
{
    const float4* xr = (const float4*)(x + (size_t)n * DIM);
    #pragma unroll
    for (int h = 0; h < NH; ++h) acc[h] = 0.f;
    #pragma unroll
    for (int q = 0; q < DIM / 4; ++q) {
        const float4 v = xr[q];
        #pragma unroll
        for (int h = 0; h < NH; ++h) {
            acc[h] += v.x * wx[4 * q + 0][h];
            acc[h] += v.y * wx[4 * q + 1][h];
            acc[h] += v.z * wx[4 * q + 2][h];
            acc[h] += v.w * wx[4 * q + 3][h];
        }
    }
}

// ---- main: one block (4 waves) per segment, one row per thread ----
__global__ __launch_bounds__(BLOCK) void seg_attn_kernel(
    const float* __restrict__ x,          // [N, 40]
    const int* __restrict__ seg_start,
    const int* __restrict__ seg_end,
    const float* __restrict__ wxg,        // [DIM*NH]
    float* __restrict__ out)              // [4, N]
{
    __shared__ float wx[DIM][NH];
    __shared__ float red_max[NWAVE][NH];
    __shared__ float red_sum[NWAVE][NH];
    __shared__ float cache_l[NH][CACHE_ROWS];   // 8 KB logit cache

    const int tid = (int)threadIdx.x;
    if (tid < DIM * NH) wx[tid >> 2][tid & 3] = wxg[tid];

    const int s = (int)blockIdx.x;
    const int start = seg_start[s];
    const int rows = seg_end[s] - start;
    __syncthreads();
    if (rows <= 0) return;   // block-uniform exit (all threads see same rows)

    const int lane = tid & 63;
    const int wid = tid >> 6;
    const int iters = (rows + BLOCK - 1) / BLOCK;   // 1 for rows<=256 (common)

    // ---- pass 1: logits -> LDS cache + lane-local max ----
    float lmax[NH];
    #pragma unroll
    for (int h = 0; h < NH; ++h) lmax[h] = -3.0e38f;

    for (int it = 0; it < iters; ++it) {
        const int i = it * BLOCK + tid;
        if (i < rows) {
            float acc[NH];
            compute_logits(x, start + i, wx, acc);
            if (i < CACHE_ROWS) {
                #pragma unroll
                for (int h = 0; h < NH; ++h) cache_l[h][i] = acc[h];
            }
            #pragma unroll
            for (int h = 0; h < NH; ++h) lmax[h] = fmaxf(lmax[h], acc[h]);
        }
    }

    // ---- block max reduce: wave shfl + LDS combine ----
    #pragma unroll
    for (int h = 0; h < NH; ++h) {
        float v = lmax[h];
        #pragma unroll
        for (int off = 32; off > 0; off >>= 1) v = fmaxf(v, __shfl_xor(v, off, 64));
        if (lane == 0) red_max[wid][h] = v;
    }
    __syncthreads();   // also publishes cache_l
    float m[NH];
    #pragma unroll
    for (int h = 0; h < NH; ++h)
        m[h] = fmaxf(fmaxf(red_max[0][h], red_max[1][h]),
                     fmaxf(red_max[2][h], red_max[3][h]));

    // ---- pass 2: exp + block sum (logits from LDS; rare tail recomputes) ----
    float lsum[NH] = {0.f, 0.f, 0.f, 0.f};
    for (int it = 0; it < iters; ++it) {
        const int i = it * BLOCK + tid;
        if (i < rows) {
            float acc[NH];
            if (i < CACHE_ROWS) {
                #pragma unroll
                for (int h = 0; h < NH; ++h) acc[h] = cache_l[h][i];
            } else {
                compute_logits(x, start + i, wx, acc);
            }
            #pragma unroll
            for (int h = 0; h < NH; ++h) lsum[h] += __expf(acc[h] - m[h]);
        }
    }

    #pragma unroll
    for (int h = 0; h < NH; ++h) {
        float v = lsum[h];
        #pragma unroll
        for (int off = 32; off > 0; off >>= 1) v += __shfl_xor(v, off, 64);
        if (lane == 0) red_sum[wid][h] = v;
    }
    __syncthreads();
    float rden[NH];
    #pragma unroll
    for (int h = 0; h < NH; ++h)
        rden[h] = 1.0f / (red_sum[0][h] + red_sum[1][h] +
                          red_sum[2][h] + red_sum[3][h]);

    // ---- pass 3: out = exp(l - m) * rden (recompute exp; coalesced per h) ----
    for (int it = 0; it < iters; ++it) {
        const int i = it * BLOCK + tid;
        if (i < rows) {
            float acc[NH];
            if (i < CACHE_ROWS) {
                #pragma unroll
                for (int h = 0; h < NH; ++h) acc[h] = cache_l[h][i];
            } else {
                compute_logits(x, start + i, wx, acc);
            }
            const int n = start + i;
            #pragma unroll
            for (int h = 0; h < NH; ++h)
                out[(size_t)h * NROWS + n] = __expf(acc[h] - m[h]) * rden[h];
        }
    }
}

extern "C" void kernel_launch(void* const* d_in, const int* in_sizes, int n_in,
                              void* d_out, int out_size, void* d_ws, size_t ws_size,
                              hipStream_t stream) {
    const float* x  = (const float*)d_in[0];
    const int* seg  = (const int*)d_in[1];
    const float* Wk = (const float*)d_in[11];
    const float* Wq = (const float*)d_in[12];
    float* out = (float*)d_out;

    int* seg_start = (int*)d_ws;                  // [NSEG]
    int* seg_end   = seg_start + NSEG;            // [NSEG]
    float* wxg     = (float*)(seg_end + NSEG);    // [DIM*NH]

    hipLaunchKernelGGL(prep_kernel, dim3((NROWS + BLOCK - 1) / BLOCK), dim3(BLOCK),
                       0, stream, seg, Wk, Wq, seg_start, seg_end, wxg);
    hipLaunchKernelGGL(seg_attn_kernel, dim3(NSEG), dim3(BLOCK),
                       0, stream, x, seg_start, seg_end, wxg, out);
}